// Round 1
// baseline (673.754 us; speedup 1.0000x reference)
//
#include <hip/hip_runtime.h>

#define D 128
#define KNOW 1024
#define ITEM 20000
#define NTOT (ITEM + KNOW)
#define LAYERS 2
#define LAT 256
#define BB 256
#define SS 200
#define H3 (3 * D)
#define CH 8

// ---------------- z = X @ W  (N x 128 @ 128 x 128) ----------------
__global__ __launch_bounds__(256) void mm_z(const float* __restrict__ X, const float* __restrict__ W,
                                            float* __restrict__ Z, int nrows) {
    __shared__ float Wl[D * D];      // 64 KB
    __shared__ float Xl[16 * D];     // 8 KB
    for (int i = threadIdx.x; i < D * D / 4; i += 256)
        ((float4*)Wl)[i] = ((const float4*)W)[i];
    int row0 = blockIdx.x * 16;
    int nr = nrows - row0; if (nr > 16) nr = 16;
    for (int i = threadIdx.x; i < nr * (D / 4); i += 256)
        ((float4*)Xl)[i] = ((const float4*)(X + (size_t)row0 * D))[i];
    __syncthreads();
    int col = threadIdx.x & (D - 1);
    int rg  = threadIdx.x >> 7;   // 0 or 1 -> rows rg*8 .. rg*8+7
    float acc[8] = {0, 0, 0, 0, 0, 0, 0, 0};
    const float4* X4 = (const float4*)Xl;
    for (int k4 = 0; k4 < D / 4; ++k4) {
        float w0 = Wl[(4 * k4 + 0) * D + col];
        float w1 = Wl[(4 * k4 + 1) * D + col];
        float w2 = Wl[(4 * k4 + 2) * D + col];
        float w3 = Wl[(4 * k4 + 3) * D + col];
#pragma unroll
        for (int r = 0; r < 8; ++r) {
            float4 xv = X4[(rg * 8 + r) * (D / 4) + k4];
            acc[r] += xv.x * w0 + xv.y * w1 + xv.z * w2 + xv.w * w3;
        }
    }
#pragma unroll
    for (int r = 0; r < 8; ++r) {
        int row = row0 + rg * 8 + r;
        if (row < nrows) Z[(size_t)row * D + col] = acc[r];
    }
}

// ---------------- d_src/d_dst = z @ a_src, z @ a_dst ----------------
__global__ __launch_bounds__(256) void dvec(const float* __restrict__ Z, const float* __restrict__ gA,
                                            float* __restrict__ dsrc, float* __restrict__ ddst, int n) {
    int row = blockIdx.x * 4 + (threadIdx.x >> 6);
    int lane = threadIdx.x & 63;
    if (row >= n) return;
    float2 zv = ((const float2*)(Z + (size_t)row * D))[lane];
    float2 as = ((const float2*)gA)[lane];
    float2 ad = ((const float2*)gA)[lane + 64];
    float vs = zv.x * as.x + zv.y * as.y;
    float vd = zv.x * ad.x + zv.y * ad.y;
#pragma unroll
    for (int o = 32; o; o >>= 1) { vs += __shfl_down(vs, o, 64); vd += __shfl_down(vd, o, 64); }
    if (lane == 0) { dsrc[row] = vs; ddst[row] = vd; }
}

// ---------------- CSR build ----------------
__global__ void hist(const int* __restrict__ dst, int E, int* __restrict__ cnt) {
    int i = blockIdx.x * blockDim.x + threadIdx.x;
    if (i < E) atomicAdd(&cnt[dst[i]], 1);
}

__global__ __launch_bounds__(1024) void exscan(int* __restrict__ cnt_cur, int* __restrict__ off, int n) {
    // in: cnt_cur[i] = counts; out: off[0..n] exclusive scan, cnt_cur[i] = off[i] (cursor)
    __shared__ int wsum[16];
    __shared__ int carry;
    int tid = threadIdx.x, lane = tid & 63, wid = tid >> 6;
    if (tid == 0) { carry = 0; off[0] = 0; }
    __syncthreads();
    for (int base = 0; base < n; base += 1024) {
        int i = base + tid;
        int v = (i < n) ? cnt_cur[i] : 0;
        int x = v;
#pragma unroll
        for (int d = 1; d < 64; d <<= 1) { int t = __shfl_up(x, d, 64); x += (lane >= d) ? t : 0; }
        if (lane == 63) wsum[wid] = x;
        __syncthreads();
        if (wid == 0) {
            int w = (lane < 16) ? wsum[lane] : 0;
#pragma unroll
            for (int d = 1; d < 16; d <<= 1) { int t = __shfl_up(w, d, 64); w += (lane >= d) ? t : 0; }
            if (lane < 16) wsum[lane] = w;
        }
        __syncthreads();
        int incl = x + ((wid > 0) ? wsum[wid - 1] : 0) + carry;
        if (i < n) { off[i + 1] = incl; cnt_cur[i] = incl - v; }
        __syncthreads();
        if (tid == 1023) carry = incl;
        __syncthreads();
    }
}

__global__ void scatter(const int* __restrict__ src, const int* __restrict__ dst, int E,
                        int* __restrict__ cur, int* __restrict__ es) {
    int i = blockIdx.x * blockDim.x + threadIdx.x;
    if (i < E) { int p = atomicAdd(&cur[dst[i]], 1); es[p] = src[i]; }
}

// ---------------- per-dst attention aggregation (one wave per dst) ----------------
__global__ __launch_bounds__(256) void agg(const float* __restrict__ Z, const float* __restrict__ dsrc,
                                           const float* __restrict__ ddst, const int* __restrict__ off,
                                           const int* __restrict__ es, float* __restrict__ out, int n) {
    int row = blockIdx.x * 4 + (threadIdx.x >> 6);
    int lane = threadIdx.x & 63;
    if (row >= n) return;
    int e0 = off[row], e1 = off[row + 1];
    float2 res = make_float2(0.f, 0.f);
    if (e1 > e0) {
        float dd = ddst[row];
        float mx = -3.4e38f;
        for (int e = e0 + lane; e < e1; e += 64) {
            float t = dsrc[es[e]] + dd;
            t = (t > 0.f) ? t : 0.01f * t;
            mx = fmaxf(mx, t);
        }
#pragma unroll
        for (int o = 32; o; o >>= 1) mx = fmaxf(mx, __shfl_xor(mx, o, 64));
        float den = 0.f, ax = 0.f, ay = 0.f;
        for (int e = e0; e < e1; ++e) {
            int s = es[e];
            float t = dsrc[s] + dd;
            t = (t > 0.f) ? t : 0.01f * t;
            float w = expf(t - mx);
            den += w;
            float2 zv = ((const float2*)(Z + (size_t)s * D))[lane];
            ax += w * zv.x; ay += w * zv.y;
        }
        float inv = 1.f / fmaxf(den, 1e-12f);
        res = make_float2(ax * inv, ay * inv);
    }
    ((float2*)(out + (size_t)row * D))[lane] = res;
}

// ---------------- ra-gate combine: kn = s0*A + s1*B ----------------
__global__ __launch_bounds__(128) void combine(const float* __restrict__ kdir, const float* __restrict__ kfe,
                                               const float* __restrict__ raW1, const float* __restrict__ raB1,
                                               const float* __restrict__ raW2, float* __restrict__ out) {
    __shared__ float A[D], Bv[D];
    __shared__ float2 red[128];
    int i = blockIdx.x, j = threadIdx.x;
    A[j]  = kdir[(size_t)i * D + j];
    Bv[j] = kfe[(size_t)(ITEM + i) * D + j];
    __syncthreads();
    float accA = raB1[j], accB = accA;
    for (int k = 0; k < D; ++k) {
        float w = raW1[k * D + j];
        accA = fmaf(A[k], w, accA);
        accB = fmaf(Bv[k], w, accB);
    }
    float w2 = raW2[j];
    float pA = tanhf(accA) * w2, pB = tanhf(accB) * w2;
    red[j] = make_float2(pA, pB);
    __syncthreads();
    for (int st = 64; st > 0; st >>= 1) {
        if (j < st) { red[j].x += red[j + st].x; red[j].y += red[j + st].y; }
        __syncthreads();
    }
    float rA = red[0].x, rB = red[0].y;
    float mx = fmaxf(rA, rB);
    float eA = expf(rA - mx), eB = expf(rB - mx), s = 1.f / (eA + eB);
    out[(size_t)(ITEM + i) * D + j] = (eA * s) * A[j] + (eB * s) * Bv[j];
}

// ---------------- masked kn_rec reduction over s ----------------
__global__ __launch_bounds__(256) void krowk(const float* __restrict__ kn_rec, const float* __restrict__ kn_num,
                                             const int* __restrict__ p_target, float* __restrict__ krow) {
    int b = blockIdx.x, ch = blockIdx.y;
    int cnt = p_target[b] + 1;
    int per = (SS + CH - 1) / CH;
    int s0 = ch * per, s1 = s0 + per;
    if (s1 > cnt) s1 = cnt;
    if (s0 >= s1) return;
    int k0 = threadIdx.x * 4;
    float4 acc = make_float4(0, 0, 0, 0);
    for (int s = s0; s < s1; ++s) {
        float inv = 1.f / kn_num[b * SS + s];
        float4 v = *(const float4*)(kn_rec + ((size_t)b * SS + s) * KNOW + k0);
        acc.x += v.x * inv; acc.y += v.y * inv; acc.z += v.z * inv; acc.w += v.w * inv;
    }
    atomicAdd(&krow[b * KNOW + k0 + 0], acc.x);
    atomicAdd(&krow[b * KNOW + k0 + 1], acc.y);
    atomicAdd(&krow[b * KNOW + k0 + 2], acc.z);
    atomicAdd(&krow[b * KNOW + k0 + 3], acc.w);
}

// ---------------- h assembly: [be_mean | ba_mean | (krow@kn)/msum] ----------------
__global__ __launch_bounds__(128) void hker(const float* __restrict__ ex, const float* __restrict__ ans_table,
                                            const int* __restrict__ p_rec, const int* __restrict__ a_rec,
                                            const int* __restrict__ p_target, const float* __restrict__ krow,
                                            const float* __restrict__ kn, float* __restrict__ h) {
    int b = blockIdx.x, j = threadIdx.x;
    int cnt = p_target[b] + 1;
    float accE = 0.f, accA = 0.f;
    for (int s = 0; s < cnt; ++s) {
        int pi = p_rec[b * SS + s];
        int ai = a_rec[b * SS + s];
        accE += ex[(size_t)pi * D + j];
        accA += ans_table[ai * D + j];
    }
    __shared__ float kr[KNOW];
    for (int i = j; i < KNOW; i += 128) kr[i] = krow[b * KNOW + i];
    __syncthreads();
    float accK = 0.f;
    for (int k = 0; k < KNOW; ++k) accK += kr[k] * kn[(size_t)k * D + j];
    float inv = 1.f / (float)cnt;
    h[b * H3 + j]         = accE * inv;
    h[b * H3 + D + j]     = accA * inv;
    h[b * H3 + 2 * D + j] = accK * inv;
}

// ---------------- hidden layers: tanh(h@W1 + b1) for act + 3 value heads ----------------
__global__ __launch_bounds__(256) void hidker(const float* __restrict__ h, const float* __restrict__ actW1,
                                              const float* __restrict__ actB1, const float* __restrict__ vW1,
                                              const float* __restrict__ vB1, float* __restrict__ hid) {
    int b = blockIdx.x, head = blockIdx.y, j = threadIdx.x;
    const float* W  = (head == 0) ? actW1 : (vW1 + (size_t)(head - 1) * H3 * LAT);
    const float* bi = (head == 0) ? actB1 : (vB1 + (head - 1) * LAT);
    __shared__ float hr[H3];
    for (int i = j; i < H3; i += 256) hr[i] = h[b * H3 + i];
    __syncthreads();
    float acc = bi[j];
    for (int k = 0; k < H3; ++k) acc += hr[k] * W[(size_t)k * LAT + j];
    hid[((size_t)head * BB + b) * LAT + j] = tanhf(acc);
}

// ---------------- logits = hid @ actW2 + actB2 ----------------
__global__ __launch_bounds__(256) void logitsker(const float* __restrict__ hid, const float* __restrict__ actW2,
                                                 const float* __restrict__ actB2, float* __restrict__ out) {
    __shared__ float ht[32 * LAT]; // 32 KB
    int b0 = blockIdx.y * 32;
    for (int idx = threadIdx.x; idx < 32 * LAT / 4; idx += 256)
        ((float4*)ht)[idx] = ((const float4*)(hid + (size_t)b0 * LAT))[idx];
    __syncthreads();
    int i = blockIdx.x * 256 + threadIdx.x;
    if (i >= ITEM) return;
    float bias = actB2[i];
    float acc[32];
#pragma unroll
    for (int r = 0; r < 32; ++r) acc[r] = bias;
    const float4* ht4 = (const float4*)ht;
    for (int l4 = 0; l4 < LAT / 4; ++l4) {
        float w0 = actW2[(size_t)(4 * l4 + 0) * ITEM + i];
        float w1 = actW2[(size_t)(4 * l4 + 1) * ITEM + i];
        float w2 = actW2[(size_t)(4 * l4 + 2) * ITEM + i];
        float w3 = actW2[(size_t)(4 * l4 + 3) * ITEM + i];
#pragma unroll
        for (int r = 0; r < 32; ++r) {
            float4 hv = ht4[r * (LAT / 4) + l4];
            acc[r] += hv.x * w0 + hv.y * w1 + hv.z * w2 + hv.w * w3;
        }
    }
#pragma unroll
    for (int r = 0; r < 32; ++r) out[(size_t)(b0 + r) * ITEM + i] = acc[r];
}

// ---------------- value heads: vals[k][b] = vh@vW2[k] + vB2[k] ----------------
__global__ __launch_bounds__(256) void valsker(const float* __restrict__ hid, const float* __restrict__ vW2,
                                               const float* __restrict__ vB2, float* __restrict__ out) {
    int idx = blockIdx.x * 4 + (threadIdx.x >> 6);
    int lane = threadIdx.x & 63;
    if (idx >= 3 * BB) return;
    int k = idx / BB, b = idx - k * BB;
    const float* vh = hid + ((size_t)(k + 1) * BB + b) * LAT;
    float4 a = ((const float4*)vh)[lane];
    float4 w = ((const float4*)(vW2 + k * LAT))[lane];
    float s = a.x * w.x + a.y * w.y + a.z * w.z + a.w * w.w;
#pragma unroll
    for (int o = 32; o; o >>= 1) s += __shfl_down(s, o, 64);
    if (lane == 0) out[(size_t)BB * ITEM + k * BB + b] = s + vB2[k];
}

extern "C" void kernel_launch(void* const* d_in, const int* in_sizes, int n_in,
                              void* d_out, int out_size, void* d_ws, size_t ws_size,
                              hipStream_t stream) {
    const int*   p_rec      = (const int*)d_in[0];
    const int*   p_target   = (const int*)d_in[1];
    const int*   a_rec      = (const int*)d_in[2];
    const float* kn_rec     = (const float*)d_in[3];
    const float* kn_num     = (const float*)d_in[4];
    const int*   src1       = (const int*)d_in[5];
    const int*   dst1       = (const int*)d_in[6];
    const int*   src2       = (const int*)d_in[7];
    const int*   dst2       = (const int*)d_in[8];
    const int*   src3       = (const int*)d_in[9];
    const int*   dst3       = (const int*)d_in[10];
    const float* kn_table   = (const float*)d_in[11];
    const float* exer_table = (const float*)d_in[12];
    const float* ans_table  = (const float*)d_in[13];
    const float* gW         = (const float*)d_in[14];
    const float* gA         = (const float*)d_in[15];
    const float* raW1       = (const float*)d_in[16];
    const float* raB1       = (const float*)d_in[17];
    const float* raW2       = (const float*)d_in[18];
    const float* actW1      = (const float*)d_in[19];
    const float* actB1      = (const float*)d_in[20];
    const float* actW2      = (const float*)d_in[21];
    const float* actB2      = (const float*)d_in[22];
    const float* vW1        = (const float*)d_in[23];
    const float* vB1        = (const float*)d_in[24];
    const float* vW2        = (const float*)d_in[25];
    const float* vB2        = (const float*)d_in[26];
    const int E1 = in_sizes[5], E2 = in_sizes[7];

    float* base = (float*)d_ws;
    size_t o = 0;
    auto alloc = [&](size_t n) -> float* { float* p = base + o; o += (n + 3) & ~(size_t)3; return p; };
    float* ek0  = alloc((size_t)NTOT * D);
    float* ek1  = alloc((size_t)NTOT * D);
    float* z    = alloc((size_t)NTOT * D);
    float* kfe  = alloc((size_t)NTOT * D);
    float* kdir = alloc((size_t)KNOW * D);
    float* dsrc = alloc(NTOT);
    float* ddst = alloc(NTOT);
    int* off1 = (int*)alloc(KNOW + 1);
    int* off2 = (int*)alloc(NTOT + 1);
    int* off3 = (int*)alloc(NTOT + 1);
    int* cur1 = (int*)alloc(KNOW + 1);
    int* cur2 = (int*)alloc(NTOT + 1);
    int* cur3 = (int*)alloc(NTOT + 1);
    int* es1  = (int*)alloc(E1);
    int* es2  = (int*)alloc(E2);
    int* es3  = (int*)alloc(E2);
    float* krow = alloc((size_t)BB * KNOW);
    float* hbuf = alloc((size_t)BB * H3);
    float* hid  = alloc((size_t)4 * BB * LAT);

    // zero histograms + krow accumulator (ws is not re-poisoned between replays)
    hipMemsetAsync(cur1, 0, sizeof(int) * (KNOW + 1), stream);
    hipMemsetAsync(cur2, 0, sizeof(int) * (NTOT + 1), stream);
    hipMemsetAsync(cur3, 0, sizeof(int) * (NTOT + 1), stream);
    hipMemsetAsync(krow, 0, sizeof(float) * (size_t)BB * KNOW, stream);

    // CSR build (dst-sorted edge lists), once per launch, reused for both layers
    hist<<<(E1 + 255) / 256, 256, 0, stream>>>(dst1, E1, cur1);
    hist<<<(E2 + 255) / 256, 256, 0, stream>>>(dst2, E2, cur2);
    hist<<<(E2 + 255) / 256, 256, 0, stream>>>(dst3, E2, cur3);
    exscan<<<1, 1024, 0, stream>>>(cur1, off1, KNOW);
    exscan<<<1, 1024, 0, stream>>>(cur2, off2, NTOT);
    exscan<<<1, 1024, 0, stream>>>(cur3, off3, NTOT);
    scatter<<<(E1 + 255) / 256, 256, 0, stream>>>(src1, dst1, E1, cur1, es1);
    scatter<<<(E2 + 255) / 256, 256, 0, stream>>>(src2, dst2, E2, cur2, es2);
    scatter<<<(E2 + 255) / 256, 256, 0, stream>>>(src3, dst3, E2, cur3, es3);

    // ek0 = [exer_table; kn_table]
    hipMemcpyAsync(ek0, exer_table, sizeof(float) * (size_t)ITEM * D, hipMemcpyDeviceToDevice, stream);
    hipMemcpyAsync(ek0 + (size_t)ITEM * D, kn_table, sizeof(float) * (size_t)KNOW * D, hipMemcpyDeviceToDevice, stream);

    float* cur = ek0;
    float* nxt = ek1;
    for (int l = 0; l < LAYERS; ++l) {
        const float* W0 = gW + (size_t)(l * 3 + 0) * D * D;
        const float* W1 = gW + (size_t)(l * 3 + 1) * D * D;
        const float* W2 = gW + (size_t)(l * 3 + 2) * D * D;
        const float* A0 = gA + (size_t)(l * 3 + 0) * 2 * D;
        const float* A1 = gA + (size_t)(l * 3 + 1) * 2 * D;
        const float* A2 = gA + (size_t)(l * 3 + 2) * 2 * D;
        // graph 1: kn -> k_dir
        mm_z<<<KNOW / 16, 256, 0, stream>>>(cur + (size_t)ITEM * D, W0, z, KNOW);
        dvec<<<(KNOW + 3) / 4, 256, 0, stream>>>(z, A0, dsrc, ddst, KNOW);
        agg<<<(KNOW + 3) / 4, 256, 0, stream>>>(z, dsrc, ddst, off1, es1, kdir, KNOW);
        // graph 2: ek -> kfe
        mm_z<<<(NTOT + 15) / 16, 256, 0, stream>>>(cur, W1, z, NTOT);
        dvec<<<(NTOT + 3) / 4, 256, 0, stream>>>(z, A1, dsrc, ddst, NTOT);
        agg<<<(NTOT + 3) / 4, 256, 0, stream>>>(z, dsrc, ddst, off2, es2, kfe, NTOT);
        // graph 3: ek -> efk, ex' = efk[:ITEM] written straight into nxt
        mm_z<<<(NTOT + 15) / 16, 256, 0, stream>>>(cur, W2, z, NTOT);
        dvec<<<(NTOT + 3) / 4, 256, 0, stream>>>(z, A2, dsrc, ddst, NTOT);
        agg<<<(NTOT + 3) / 4, 256, 0, stream>>>(z, dsrc, ddst, off3, es3, nxt, NTOT);
        // kn' = gated mix of k_dir and kfe[ITEM:], into nxt[ITEM:]
        combine<<<KNOW, 128, 0, stream>>>(kdir, kfe, raW1 + (size_t)l * D * D, raB1 + (size_t)l * D,
                                          raW2 + (size_t)l * D, nxt);
        float* t = cur; cur = nxt; nxt = t;
    }

    // pooling + heads
    krowk<<<dim3(BB, CH), 256, 0, stream>>>(kn_rec, kn_num, p_target, krow);
    hker<<<BB, 128, 0, stream>>>(cur, ans_table, p_rec, a_rec, p_target, krow, cur + (size_t)ITEM * D, hbuf);
    hidker<<<dim3(BB, 4), 256, 0, stream>>>(hbuf, actW1, actB1, vW1, vB1, hid);
    logitsker<<<dim3((ITEM + 255) / 256, BB / 32), 256, 0, stream>>>(hid, actW2, actB2, (float*)d_out);
    valsker<<<(3 * BB + 3) / 4, 256, 0, stream>>>(hid, vW2, vB2, (float*)d_out);
}